// Round 1
// baseline (3039.990 us; speedup 1.0000x reference)
//
#include <hip/hip_runtime.h>

#define NN 100000
#define NE 3200000
#define DD 256
#define KC 4

// ---------------------------------------------------------------- CSR build

__global__ __launch_bounds__(256) void k_hist(const int* __restrict__ row,
                                              int* __restrict__ counts) {
    int e = blockIdx.x * 256 + threadIdx.x;
    if (e < NE) atomicAdd(&counts[row[e]], 1);
}

// pass1: blocks of 1024 (256 thr x 4 items): local exclusive scan + block sums
__global__ __launch_bounds__(256) void k_scan1(const int* __restrict__ counts,
                                               int* __restrict__ offs,
                                               int* __restrict__ bsum) {
    __shared__ int s[256];
    const int t = threadIdx.x;
    const int base = blockIdx.x * 1024 + t * 4;
    int v[4];
    int sum = 0;
#pragma unroll
    for (int i = 0; i < 4; ++i) {
        v[i] = (base + i < NN) ? counts[base + i] : 0;
        sum += v[i];
    }
    s[t] = sum;
    __syncthreads();
    // Hillis-Steele inclusive scan over 256 partials
    for (int off = 1; off < 256; off <<= 1) {
        int x = (t >= off) ? s[t - off] : 0;
        __syncthreads();
        s[t] += x;
        __syncthreads();
    }
    int run = (t > 0) ? s[t - 1] : 0;
#pragma unroll
    for (int i = 0; i < 4; ++i) {
        if (base + i < NN) offs[base + i] = run;
        run += v[i];
    }
    if (t == 255) bsum[blockIdx.x] = s[255];
}

__global__ void k_scan2(int* __restrict__ bsum, int nb) {
    if (threadIdx.x == 0 && blockIdx.x == 0) {
        int run = 0;
        for (int i = 0; i < nb; ++i) {
            int c = bsum[i];
            bsum[i] = run;
            run += c;
        }
    }
}

__global__ __launch_bounds__(256) void k_scan3(int* __restrict__ offs,
                                               const int* __restrict__ bsum) {
    int i = blockIdx.x * 256 + threadIdx.x;
    if (i < NN)
        offs[i] += bsum[i >> 10];
    else if (i == NN)
        offs[NN] = NE;
}

__global__ __launch_bounds__(256) void k_fill(const int* __restrict__ row,
                                              const int* __restrict__ col,
                                              const float* __restrict__ val,
                                              const int* __restrict__ offs,
                                              int* __restrict__ cursor,
                                              int* __restrict__ cols_s,
                                              float* __restrict__ vals_s) {
    int e = blockIdx.x * 256 + threadIdx.x;
    if (e >= NE) return;
    int r = row[e];
    int p = offs[r] + atomicAdd(&cursor[r], 1);
    cols_s[p] = col[e];
    vals_s[p] = val[e];
}

// ---------------------------------------------------------------- GEMM fp32
// Y[M,256] = (alpha*X1 + beta*X2) @ W[256,256]; X2 may be null (use X1 raw).
// 64x64 tile, BK=16, 16x16 threads, 4x4 per thread.

__global__ __launch_bounds__(256) void k_gemm(const float* __restrict__ X1,
                                              const float* __restrict__ X2,
                                              float alpha, float beta,
                                              const float* __restrict__ W,
                                              float* __restrict__ Y) {
    __shared__ float As[16][68];  // [k][m], stride 68 floats = 272B (16B-aligned rows)
    __shared__ float Bs[16][68];  // [k][n]

    const int tid = threadIdx.x;
    const int tx = tid & 15, ty = tid >> 4;
    const int bm = blockIdx.y * 64;
    const int bn = blockIdx.x * 64;

    const int am = tid >> 2;         // 0..63 : A row within tile
    const int ak = (tid & 3) * 4;    // 0,4,8,12 : A k within tile
    const int bk = tid >> 4;         // 0..15 : B k within tile
    const int bn4 = (tid & 15) * 4;  // B n within tile

    float acc[4][4] = {};

    for (int k0 = 0; k0 < DD; k0 += 16) {
        // A tile (with fused blend)
        {
            const int m = bm + am;
            float4 v = make_float4(0.f, 0.f, 0.f, 0.f);
            if (m < NN) {
                const size_t idx = (size_t)m * DD + k0 + ak;
                float4 v1 = *reinterpret_cast<const float4*>(X1 + idx);
                if (X2) {
                    float4 v2 = *reinterpret_cast<const float4*>(X2 + idx);
                    v.x = alpha * v1.x + beta * v2.x;
                    v.y = alpha * v1.y + beta * v2.y;
                    v.z = alpha * v1.z + beta * v2.z;
                    v.w = alpha * v1.w + beta * v2.w;
                } else {
                    v = v1;
                }
            }
            As[ak + 0][am] = v.x;
            As[ak + 1][am] = v.y;
            As[ak + 2][am] = v.z;
            As[ak + 3][am] = v.w;
        }
        // B tile
        {
            const float4 w = *reinterpret_cast<const float4*>(W + (size_t)(k0 + bk) * DD + bn + bn4);
            *reinterpret_cast<float4*>(&Bs[bk][bn4]) = w;
        }
        __syncthreads();
#pragma unroll
        for (int kk = 0; kk < 16; ++kk) {
            float4 av = *reinterpret_cast<const float4*>(&As[kk][ty * 4]);
            float4 bv = *reinterpret_cast<const float4*>(&Bs[kk][tx * 4]);
            float a[4] = {av.x, av.y, av.z, av.w};
            float b[4] = {bv.x, bv.y, bv.z, bv.w};
#pragma unroll
            for (int i = 0; i < 4; ++i)
#pragma unroll
                for (int j = 0; j < 4; ++j) acc[i][j] += a[i] * b[j];
        }
        __syncthreads();
    }

#pragma unroll
    for (int i = 0; i < 4; ++i) {
        const int m = bm + ty * 4 + i;
        if (m < NN) {
            float4 o = make_float4(acc[i][0], acc[i][1], acc[i][2], acc[i][3]);
            *reinterpret_cast<float4*>(Y + (size_t)m * DD + bn + tx * 4) = o;
        }
    }
}

// ---------------------------------------------------------------- SpMM (D=256)
// H[i,:] = (relu)( sum_e vals[e] * Y[cols[e],:] ), one wave per row, float4/lane.

__global__ __launch_bounds__(256) void k_spmm(const int* __restrict__ offs,
                                              const int* __restrict__ cols,
                                              const float* __restrict__ vals,
                                              const float* __restrict__ Y,
                                              float* __restrict__ H, int relu) {
    const int row = blockIdx.x * 4 + (threadIdx.x >> 6);
    if (row >= NN) return;
    const int lane = threadIdx.x & 63;
    const int e0 = offs[row], e1 = offs[row + 1];
    float ax = 0.f, ay = 0.f, az = 0.f, aw = 0.f;
    for (int e = e0; e < e1; ++e) {
        const float v = vals[e];
        const int c = cols[e];
        const float4 y = *reinterpret_cast<const float4*>(Y + (size_t)c * DD + lane * 4);
        ax += v * y.x;
        ay += v * y.y;
        az += v * y.z;
        aw += v * y.w;
    }
    if (relu) {
        ax = fmaxf(ax, 0.f);
        ay = fmaxf(ay, 0.f);
        az = fmaxf(az, 0.f);
        aw = fmaxf(aw, 0.f);
    }
    float4 o = make_float4(ax, ay, az, aw);
    *reinterpret_cast<float4*>(H + (size_t)row * DD + lane * 4) = o;
}

// ---------------------------------------------------------------- layer 5 + tail

__device__ inline float wred(float v) {
#pragma unroll
    for (int o = 32; o; o >>= 1) v += __shfl_down(v, o);
    return v;
}

// Y5[N,4] = (0.5H + 0.5z) @ W5[256,4], one wave per row
__global__ __launch_bounds__(256) void k_gemm5(const float* __restrict__ H,
                                               const float* __restrict__ z,
                                               const float* __restrict__ W5,
                                               float* __restrict__ Y5) {
    const int row = blockIdx.x * 4 + (threadIdx.x >> 6);
    if (row >= NN) return;
    const int lane = threadIdx.x & 63;
    const float4 h4 = *reinterpret_cast<const float4*>(H + (size_t)row * DD + lane * 4);
    const float4 z4 = *reinterpret_cast<const float4*>(z + (size_t)row * DD + lane * 4);
    float hv[4] = {h4.x, h4.y, h4.z, h4.w};
    float zv[4] = {z4.x, z4.y, z4.z, z4.w};
    float ax = 0.f, ay = 0.f, az = 0.f, aw = 0.f;
#pragma unroll
    for (int i = 0; i < 4; ++i) {
        const float b = 0.5f * hv[i] + 0.5f * zv[i];
        const float4 w = *reinterpret_cast<const float4*>(W5 + (size_t)(lane * 4 + i) * KC);
        ax += b * w.x;
        ay += b * w.y;
        az += b * w.z;
        aw += b * w.w;
    }
    ax = wred(ax);
    ay = wred(ay);
    az = wred(az);
    aw = wred(aw);
    if (lane == 0) {
        *reinterpret_cast<float4*>(Y5 + (size_t)row * KC) = make_float4(ax, ay, az, aw);
    }
}

// logits[i] = sum_e vals[e]*Y5[cols[e],:]; out[i,0:4] = softmax(logits)
__global__ __launch_bounds__(256) void k_sm5(const int* __restrict__ offs,
                                             const int* __restrict__ cols,
                                             const float* __restrict__ vals,
                                             const float* __restrict__ Y5,
                                             float* __restrict__ out) {
    const int row = blockIdx.x * 4 + (threadIdx.x >> 6);
    if (row >= NN) return;
    const int lane = threadIdx.x & 63;
    const int e0 = offs[row], e1 = offs[row + 1];
    float ax = 0.f, ay = 0.f, az = 0.f, aw = 0.f;
    for (int e = e0 + lane; e < e1; e += 64) {
        const float v = vals[e];
        const int c = cols[e];
        const float4 y = *reinterpret_cast<const float4*>(Y5 + (size_t)c * KC);
        ax += v * y.x;
        ay += v * y.y;
        az += v * y.z;
        aw += v * y.w;
    }
    ax = wred(ax);
    ay = wred(ay);
    az = wred(az);
    aw = wred(aw);
    if (lane == 0) {
        float m = fmaxf(fmaxf(ax, ay), fmaxf(az, aw));
        float ex = __expf(ax - m), ey = __expf(ay - m), ez = __expf(az - m), ew = __expf(aw - m);
        float s = ex + ey + ez + ew;
        float inv = 1.f / s;
        *reinterpret_cast<float4*>(out + (size_t)row * 8) =
            make_float4(ex * inv, ey * inv, ez * inv, ew * inv);
    }
}

// out[i,4:8] = normalized 1/(1+||z_i-mu_j||^2)   (V=1 so the power is identity)
__global__ __launch_bounds__(256) void k_q(const float* __restrict__ z,
                                           const float* __restrict__ cl,
                                           float* __restrict__ out) {
    const int row = blockIdx.x * 4 + (threadIdx.x >> 6);
    if (row >= NN) return;
    const int lane = threadIdx.x & 63;
    const float4 z4 = *reinterpret_cast<const float4*>(z + (size_t)row * DD + lane * 4);
    float zz = z4.x * z4.x + z4.y * z4.y + z4.z * z4.z + z4.w * z4.w;
    float dots[4], ccs[4];
#pragma unroll
    for (int j = 0; j < 4; ++j) {
        const float4 c4 = *reinterpret_cast<const float4*>(cl + (size_t)j * DD + lane * 4);
        dots[j] = z4.x * c4.x + z4.y * c4.y + z4.z * c4.z + z4.w * c4.w;
        ccs[j] = c4.x * c4.x + c4.y * c4.y + c4.z * c4.z + c4.w * c4.w;
    }
    zz = wred(zz);
#pragma unroll
    for (int j = 0; j < 4; ++j) {
        dots[j] = wred(dots[j]);
        ccs[j] = wred(ccs[j]);
    }
    if (lane == 0) {
        float q[4], s = 0.f;
#pragma unroll
        for (int j = 0; j < 4; ++j) {
            const float d2 = zz - 2.f * dots[j] + ccs[j];
            q[j] = 1.f / (1.f + d2);
            s += q[j];
        }
        const float inv = 1.f / s;
        *reinterpret_cast<float4*>(out + (size_t)row * 8 + 4) =
            make_float4(q[0] * inv, q[1] * inv, q[2] * inv, q[3] * inv);
    }
}

// ---------------------------------------------------------------- launch

extern "C" void kernel_launch(void* const* d_in, const int* in_sizes, int n_in,
                              void* d_out, int out_size, void* d_ws, size_t ws_size,
                              hipStream_t stream) {
    const float* enc = (const float*)d_in[0];
    const float* tra1 = (const float*)d_in[1];
    const float* tra2 = (const float*)d_in[2];
    const float* tra3 = (const float*)d_in[3];
    const float* z = (const float*)d_in[4];
    const int* erow = (const int*)d_in[5];
    const int* ecol = (const int*)d_in[6];
    const float* evals = (const float*)d_in[7];
    const float* W1 = (const float*)d_in[8];
    const float* W2 = (const float*)d_in[9];
    const float* W3 = (const float*)d_in[10];
    const float* W4 = (const float*)d_in[11];
    const float* W5 = (const float*)d_in[12];
    const float* cluster = (const float*)d_in[13];
    float* out = (float*)d_out;

    char* ws = (char*)d_ws;
    size_t off = 0;
    auto take = [&](size_t bytes) -> void* {
        void* p = ws + off;
        off = (off + bytes + 255) & ~(size_t)255;
        return p;
    };
    int* counts = (int*)take((size_t)NN * 4);
    int* cursor = (int*)take((size_t)NN * 4);
    int* offs = (int*)take((size_t)(NN + 1) * 4);
    int* bsum = (int*)take(4096);
    int* cols_s = (int*)take((size_t)NE * 4);
    float* vals_s = (float*)take((size_t)NE * 4);
    float* Y = (float*)take((size_t)NN * DD * 4);
    float* H = (float*)take((size_t)NN * DD * 4);
    float* Y5 = (float*)take((size_t)NN * KC * 4);

    hipMemsetAsync(counts, 0, (size_t)NN * 4, stream);
    hipMemsetAsync(cursor, 0, (size_t)NN * 4, stream);

    k_hist<<<(NE + 255) / 256, 256, 0, stream>>>(erow, counts);
    const int nsb = (NN + 1023) / 1024;  // 98
    k_scan1<<<nsb, 256, 0, stream>>>(counts, offs, bsum);
    k_scan2<<<1, 64, 0, stream>>>(bsum, nsb);
    k_scan3<<<(NN + 256) / 256, 256, 0, stream>>>(offs, bsum);
    k_fill<<<(NE + 255) / 256, 256, 0, stream>>>(erow, ecol, evals, offs, cursor, cols_s, vals_s);

    dim3 gg(DD / 64, (NN + 63) / 64);
    const int rb = NN / 4;  // 25000 row-blocks (4 waves each)

    k_gemm<<<gg, 256, 0, stream>>>(enc, nullptr, 1.f, 0.f, W1, Y);
    k_spmm<<<rb, 256, 0, stream>>>(offs, cols_s, vals_s, Y, H, 1);

    k_gemm<<<gg, 256, 0, stream>>>(H, tra1, 0.5f, 0.5f, W2, Y);
    k_spmm<<<rb, 256, 0, stream>>>(offs, cols_s, vals_s, Y, H, 1);

    k_gemm<<<gg, 256, 0, stream>>>(H, tra2, 0.5f, 0.5f, W3, Y);
    k_spmm<<<rb, 256, 0, stream>>>(offs, cols_s, vals_s, Y, H, 1);

    k_gemm<<<gg, 256, 0, stream>>>(H, tra3, 0.5f, 0.5f, W4, Y);
    k_spmm<<<rb, 256, 0, stream>>>(offs, cols_s, vals_s, Y, H, 1);

    k_gemm5<<<rb, 256, 0, stream>>>(H, z, W5, Y5);
    k_sm5<<<rb, 256, 0, stream>>>(offs, cols_s, vals_s, Y5, out);
    k_q<<<rb, 256, 0, stream>>>(z, cluster, out);
}

// Round 2
// 1553.027 us; speedup vs baseline: 1.9575x; 1.9575x over previous
//
#include <hip/hip_runtime.h>

#define NN 100000
#define NE 3200000
#define DD 256
#define KC 4
#define MPAD 100096  // 782 * 128

typedef _Float16 f16x8 __attribute__((ext_vector_type(8)));
typedef _Float16 f16x4 __attribute__((ext_vector_type(4)));
typedef float f32x4 __attribute__((ext_vector_type(4)));

// ---------------------------------------------------------------- CSR build

__global__ __launch_bounds__(256) void k_hist(const int* __restrict__ row,
                                              int* __restrict__ counts) {
    int e = blockIdx.x * 256 + threadIdx.x;
    if (e < NE) atomicAdd(&counts[row[e]], 1);
}

__global__ __launch_bounds__(256) void k_scan1(const int* __restrict__ counts,
                                               int* __restrict__ offs,
                                               int* __restrict__ bsum) {
    __shared__ int s[256];
    const int t = threadIdx.x;
    const int base = blockIdx.x * 1024 + t * 4;
    int v[4];
    int sum = 0;
#pragma unroll
    for (int i = 0; i < 4; ++i) {
        v[i] = (base + i < NN) ? counts[base + i] : 0;
        sum += v[i];
    }
    s[t] = sum;
    __syncthreads();
    for (int off = 1; off < 256; off <<= 1) {
        int x = (t >= off) ? s[t - off] : 0;
        __syncthreads();
        s[t] += x;
        __syncthreads();
    }
    int run = (t > 0) ? s[t - 1] : 0;
#pragma unroll
    for (int i = 0; i < 4; ++i) {
        if (base + i < NN) offs[base + i] = run;
        run += v[i];
    }
    if (t == 255) bsum[blockIdx.x] = s[255];
}

__global__ void k_scan2(int* __restrict__ bsum, int nb) {
    if (threadIdx.x == 0 && blockIdx.x == 0) {
        int run = 0;
        for (int i = 0; i < nb; ++i) {
            int c = bsum[i];
            bsum[i] = run;
            run += c;
        }
    }
}

__global__ __launch_bounds__(256) void k_scan3(int* __restrict__ offs,
                                               const int* __restrict__ bsum) {
    int i = blockIdx.x * 256 + threadIdx.x;
    if (i < NN)
        offs[i] += bsum[i >> 10];
    else if (i == NN)
        offs[NN] = NE;
}

__global__ __launch_bounds__(256) void k_fill(const int* __restrict__ row,
                                              const int* __restrict__ col,
                                              const float* __restrict__ val,
                                              const int* __restrict__ offs,
                                              int* __restrict__ cursor,
                                              int* __restrict__ cols_s,
                                              float* __restrict__ vals_s) {
    int e = blockIdx.x * 256 + threadIdx.x;
    if (e >= NE) return;
    int r = row[e];
    int p = offs[r] + atomicAdd(&cursor[r], 1);
    cols_s[p] = col[e];
    vals_s[p] = val[e];
}

// ---------------------------------------------------------------- fp16 converts

// X1h = fp16(enc), 8 elems/thread
__global__ __launch_bounds__(256) void k_cvtX(const float* __restrict__ in,
                                              _Float16* __restrict__ out) {
    const size_t base = ((size_t)blockIdx.x * 256 + threadIdx.x) * 8;
    if (base >= (size_t)NN * DD) return;
    float4 v0 = *reinterpret_cast<const float4*>(in + base);
    float4 v1 = *reinterpret_cast<const float4*>(in + base + 4);
    f16x8 o;
    o[0] = (_Float16)v0.x; o[1] = (_Float16)v0.y; o[2] = (_Float16)v0.z; o[3] = (_Float16)v0.w;
    o[4] = (_Float16)v1.x; o[5] = (_Float16)v1.y; o[6] = (_Float16)v1.z; o[7] = (_Float16)v1.w;
    *reinterpret_cast<f16x8*>(out + base) = o;
}

// Wt[z][n][k] = fp16(W_z[k][n]) — LDS-tiled transpose, grid (8,8,4), block 256
__global__ __launch_bounds__(256) void k_cvtW(const float* __restrict__ W1,
                                              const float* __restrict__ W2,
                                              const float* __restrict__ W3,
                                              const float* __restrict__ W4,
                                              _Float16* __restrict__ Wt) {
    __shared__ float s[32][33];
    const float* W = (blockIdx.z == 0) ? W1 : (blockIdx.z == 1) ? W2 : (blockIdx.z == 2) ? W3 : W4;
    _Float16* o = Wt + (size_t)blockIdx.z * DD * DD;
    const int bk = blockIdx.x * 32;  // k base
    const int bn = blockIdx.y * 32;  // n base
    const int tx = threadIdx.x & 31, ty = threadIdx.x >> 5;
    for (int r = ty; r < 32; r += 8) s[r][tx] = W[(size_t)(bk + r) * DD + bn + tx];
    __syncthreads();
    for (int r = ty; r < 32; r += 8) o[(size_t)(bn + r) * DD + bk + tx] = (_Float16)s[tx][r];
}

// ---------------------------------------------------------------- GEMM fp16 MFMA
// Y[M,256] = X[M,256] @ W  with X fp16 [M][K], Wt fp16 [N][K] (pre-transposed).
// BM=128, BN=256, BK=32, 512 threads (8 waves, 2x4), wave tile 64x64.
// LDS: A 2x8KB + B 2x16KB = 48KB, staged via global_load_lds w=16,
// 16B-unit XOR swizzle (cb ^= ((row>>1)&3)<<4) for conflict-free ds_read_b128.

__device__ __forceinline__ void load_lds16(const void* g, void* l) {
    __builtin_amdgcn_global_load_lds((const __attribute__((address_space(1))) void*)g,
                                     (__attribute__((address_space(3))) void*)l, 16, 0, 0);
}

__global__ __launch_bounds__(512, 4) void k_gemm_h(const _Float16* __restrict__ X,
                                                   const _Float16* __restrict__ Wt,
                                                   _Float16* __restrict__ Y) {
    __shared__ __align__(16) char lds[49152];  // A[2][8192] | B[2][16384]
    char* const Albase = lds;
    char* const Blbase = lds + 16384;

    const int tid = threadIdx.x;
    const int lane = tid & 63;
    const int wid = tid >> 6;
    const int wr = wid >> 2;   // 0..1
    const int wc = wid & 3;    // 0..3
    const int bm = blockIdx.x * 128;

    // staging geometry (per-lane global addr, wave-uniform LDS base)
    const int aoffl = wid * 1024 + lane * 16;        // A: byte off in 8KB tile
    const int arw = aoffl >> 6;                      // row 0..127
    const int acb = (aoffl & 63) ^ (((arw >> 1) & 3) << 4);
    const char* const Asrc0 = (const char*)X + ((size_t)(bm + arw) * DD) * 2 + acb;
    char* const Adst0 = Albase + wid * 1024;

    const int boffl0 = wid * 1024 + lane * 16;       // B slot 0
    const int brw0 = boffl0 >> 6;
    const int bcb0 = (boffl0 & 63) ^ (((brw0 >> 1) & 3) << 4);
    const char* const Bsrc0 = (const char*)Wt + ((size_t)brw0 * DD) * 2 + bcb0;
    const int boffl1 = 8192 + wid * 1024 + lane * 16;  // B slot 1
    const int brw1 = boffl1 >> 6;
    const int bcb1 = (boffl1 & 63) ^ (((brw1 >> 1) & 3) << 4);
    const char* const Bsrc1 = (const char*)Wt + ((size_t)brw1 * DD) * 2 + bcb1;
    char* const Bdst0 = Blbase + wid * 1024;
    char* const Bdst1 = Blbase + 8192 + wid * 1024;

    // fragment read offsets (swizzled)
    int aro[4], bro[4];
#pragma unroll
    for (int m = 0; m < 4; ++m) {
        const int r = wr * 64 + m * 16 + (lane & 15);
        aro[m] = r * 64 + ((((lane >> 4) * 16)) ^ (((r >> 1) & 3) << 4));
    }
#pragma unroll
    for (int n = 0; n < 4; ++n) {
        const int r = wc * 64 + n * 16 + (lane & 15);
        bro[n] = r * 64 + ((((lane >> 4) * 16)) ^ (((r >> 1) & 3) << 4));
    }

    f32x4 acc[4][4];
#pragma unroll
    for (int m = 0; m < 4; ++m)
#pragma unroll
        for (int n = 0; n < 4; ++n) acc[m][n] = (f32x4){0.f, 0.f, 0.f, 0.f};

    // prologue: stage kt=0 into buf 0
    load_lds16(Asrc0, Adst0);
    load_lds16(Bsrc0, Bdst0);
    load_lds16(Bsrc1 , Bdst1);
    __syncthreads();

    for (int kt = 0; kt < 8; ++kt) {
        const int cur = kt & 1;
        if (kt < 7) {
            const size_t kb = (size_t)(kt + 1) * 32 * 2;  // k byte offset
            load_lds16(Asrc0 + kb, Adst0 + (cur ^ 1) * 8192);
            load_lds16(Bsrc0 + kb, Bdst0 + (cur ^ 1) * 16384);
            load_lds16(Bsrc1 + kb, Bdst1 + (cur ^ 1) * 16384);
        }
        const char* Ab = Albase + cur * 8192;
        const char* Bb = Blbase + cur * 16384;
        f16x8 af[4], bf[4];
#pragma unroll
        for (int m = 0; m < 4; ++m) af[m] = *reinterpret_cast<const f16x8*>(Ab + aro[m]);
#pragma unroll
        for (int n = 0; n < 4; ++n) bf[n] = *reinterpret_cast<const f16x8*>(Bb + bro[n]);
#pragma unroll
        for (int m = 0; m < 4; ++m)
#pragma unroll
            for (int n = 0; n < 4; ++n)
                acc[m][n] = __builtin_amdgcn_mfma_f32_16x16x32_f16(af[m], bf[n], acc[m][n], 0, 0, 0);
        __syncthreads();
    }

    // epilogue: C layout col=lane&15, row=(lane>>4)*4+j
#pragma unroll
    for (int m = 0; m < 4; ++m) {
        const int row = bm + wr * 64 + m * 16 + (lane >> 4) * 4;
#pragma unroll
        for (int n = 0; n < 4; ++n) {
            const int col = wc * 64 + n * 16 + (lane & 15);
#pragma unroll
            for (int j = 0; j < 4; ++j)
                Y[(size_t)(row + j) * DD + col] = (_Float16)acc[m][n][j];
        }
    }
}

// ---------------------------------------------------------------- SpMM fp16
// Xout[i,:] = fp16( 0.5*relu(sum_e vals[e]*Y[cols[e],:]) + 0.5*blend[i,:] )

__global__ __launch_bounds__(256) void k_spmm_h(const int* __restrict__ offs,
                                                const int* __restrict__ cols,
                                                const float* __restrict__ vals,
                                                const _Float16* __restrict__ Y,
                                                const float* __restrict__ blend,
                                                _Float16* __restrict__ Xout) {
    const int row = blockIdx.x * 4 + (threadIdx.x >> 6);
    if (row >= NN) return;
    const int lane = threadIdx.x & 63;
    const int e0 = offs[row], e1 = offs[row + 1];
    float a0 = 0.f, a1 = 0.f, a2 = 0.f, a3 = 0.f;
    int e = e0;
    for (; e + 4 <= e1; e += 4) {
        const int c0 = cols[e], c1 = cols[e + 1], c2 = cols[e + 2], c3 = cols[e + 3];
        const float v0 = vals[e], v1 = vals[e + 1], v2 = vals[e + 2], v3 = vals[e + 3];
        const f16x4 y0 = *reinterpret_cast<const f16x4*>(Y + (size_t)c0 * DD + lane * 4);
        const f16x4 y1 = *reinterpret_cast<const f16x4*>(Y + (size_t)c1 * DD + lane * 4);
        const f16x4 y2 = *reinterpret_cast<const f16x4*>(Y + (size_t)c2 * DD + lane * 4);
        const f16x4 y3 = *reinterpret_cast<const f16x4*>(Y + (size_t)c3 * DD + lane * 4);
        a0 += v0 * (float)y0[0] + v1 * (float)y1[0] + v2 * (float)y2[0] + v3 * (float)y3[0];
        a1 += v0 * (float)y0[1] + v1 * (float)y1[1] + v2 * (float)y2[1] + v3 * (float)y3[1];
        a2 += v0 * (float)y0[2] + v1 * (float)y1[2] + v2 * (float)y2[2] + v3 * (float)y3[2];
        a3 += v0 * (float)y0[3] + v1 * (float)y1[3] + v2 * (float)y2[3] + v3 * (float)y3[3];
    }
    for (; e < e1; ++e) {
        const float v = vals[e];
        const f16x4 y = *reinterpret_cast<const f16x4*>(Y + (size_t)cols[e] * DD + lane * 4);
        a0 += v * (float)y[0];
        a1 += v * (float)y[1];
        a2 += v * (float)y[2];
        a3 += v * (float)y[3];
    }
    const float4 t = *reinterpret_cast<const float4*>(blend + (size_t)row * DD + lane * 4);
    f16x4 o;
    o[0] = (_Float16)(0.5f * fmaxf(a0, 0.f) + 0.5f * t.x);
    o[1] = (_Float16)(0.5f * fmaxf(a1, 0.f) + 0.5f * t.y);
    o[2] = (_Float16)(0.5f * fmaxf(a2, 0.f) + 0.5f * t.z);
    o[3] = (_Float16)(0.5f * fmaxf(a3, 0.f) + 0.5f * t.w);
    *reinterpret_cast<f16x4*>(Xout + (size_t)row * DD + lane * 4) = o;
}

// ---------------------------------------------------------------- layer 5 + tail

__device__ inline float wred(float v) {
#pragma unroll
    for (int o = 32; o; o >>= 1) v += __shfl_down(v, o);
    return v;
}

// Y5[N,4] = X5h @ W5[256,4]  (X5h already = fp16(0.5h+0.5z))
__global__ __launch_bounds__(256) void k_gemm5(const _Float16* __restrict__ X5,
                                               const float* __restrict__ W5,
                                               float* __restrict__ Y5) {
    const int row = blockIdx.x * 4 + (threadIdx.x >> 6);
    if (row >= NN) return;
    const int lane = threadIdx.x & 63;
    const f16x4 x4 = *reinterpret_cast<const f16x4*>(X5 + (size_t)row * DD + lane * 4);
    float ax = 0.f, ay = 0.f, az = 0.f, aw = 0.f;
#pragma unroll
    for (int i = 0; i < 4; ++i) {
        const float b = (float)x4[i];
        const float4 w = *reinterpret_cast<const float4*>(W5 + (size_t)(lane * 4 + i) * KC);
        ax += b * w.x;
        ay += b * w.y;
        az += b * w.z;
        aw += b * w.w;
    }
    ax = wred(ax);
    ay = wred(ay);
    az = wred(az);
    aw = wred(aw);
    if (lane == 0) {
        *reinterpret_cast<float4*>(Y5 + (size_t)row * KC) = make_float4(ax, ay, az, aw);
    }
}

__global__ __launch_bounds__(256) void k_sm5(const int* __restrict__ offs,
                                             const int* __restrict__ cols,
                                             const float* __restrict__ vals,
                                             const float* __restrict__ Y5,
                                             float* __restrict__ out) {
    const int row = blockIdx.x * 4 + (threadIdx.x >> 6);
    if (row >= NN) return;
    const int lane = threadIdx.x & 63;
    const int e0 = offs[row], e1 = offs[row + 1];
    float ax = 0.f, ay = 0.f, az = 0.f, aw = 0.f;
    for (int e = e0 + lane; e < e1; e += 64) {
        const float v = vals[e];
        const float4 y = *reinterpret_cast<const float4*>(Y5 + (size_t)cols[e] * KC);
        ax += v * y.x;
        ay += v * y.y;
        az += v * y.z;
        aw += v * y.w;
    }
    ax = wred(ax);
    ay = wred(ay);
    az = wred(az);
    aw = wred(aw);
    if (lane == 0) {
        float m = fmaxf(fmaxf(ax, ay), fmaxf(az, aw));
        float ex = __expf(ax - m), ey = __expf(ay - m), ez = __expf(az - m), ew = __expf(aw - m);
        float inv = 1.f / (ex + ey + ez + ew);
        *reinterpret_cast<float4*>(out + (size_t)row * 8) =
            make_float4(ex * inv, ey * inv, ez * inv, ew * inv);
    }
}

__global__ __launch_bounds__(256) void k_q(const float* __restrict__ z,
                                           const float* __restrict__ cl,
                                           float* __restrict__ out) {
    const int row = blockIdx.x * 4 + (threadIdx.x >> 6);
    if (row >= NN) return;
    const int lane = threadIdx.x & 63;
    const float4 z4 = *reinterpret_cast<const float4*>(z + (size_t)row * DD + lane * 4);
    float zz = z4.x * z4.x + z4.y * z4.y + z4.z * z4.z + z4.w * z4.w;
    float dots[4], ccs[4];
#pragma unroll
    for (int j = 0; j < 4; ++j) {
        const float4 c4 = *reinterpret_cast<const float4*>(cl + (size_t)j * DD + lane * 4);
        dots[j] = z4.x * c4.x + z4.y * c4.y + z4.z * c4.z + z4.w * c4.w;
        ccs[j] = c4.x * c4.x + c4.y * c4.y + c4.z * c4.z + c4.w * c4.w;
    }
    zz = wred(zz);
#pragma unroll
    for (int j = 0; j < 4; ++j) {
        dots[j] = wred(dots[j]);
        ccs[j] = wred(ccs[j]);
    }
    if (lane == 0) {
        float q[4], s = 0.f;
#pragma unroll
        for (int j = 0; j < 4; ++j) {
            const float d2 = zz - 2.f * dots[j] + ccs[j];
            q[j] = 1.f / (1.f + d2);
            s += q[j];
        }
        const float inv = 1.f / s;
        *reinterpret_cast<float4*>(out + (size_t)row * 8 + 4) =
            make_float4(q[0] * inv, q[1] * inv, q[2] * inv, q[3] * inv);
    }
}

// ---------------------------------------------------------------- launch

extern "C" void kernel_launch(void* const* d_in, const int* in_sizes, int n_in,
                              void* d_out, int out_size, void* d_ws, size_t ws_size,
                              hipStream_t stream) {
    const float* enc = (const float*)d_in[0];
    const float* tra1 = (const float*)d_in[1];
    const float* tra2 = (const float*)d_in[2];
    const float* tra3 = (const float*)d_in[3];
    const float* z = (const float*)d_in[4];
    const int* erow = (const int*)d_in[5];
    const int* ecol = (const int*)d_in[6];
    const float* evals = (const float*)d_in[7];
    const float* W1 = (const float*)d_in[8];
    const float* W2 = (const float*)d_in[9];
    const float* W3 = (const float*)d_in[10];
    const float* W4 = (const float*)d_in[11];
    const float* W5 = (const float*)d_in[12];
    const float* cluster = (const float*)d_in[13];
    float* out = (float*)d_out;

    char* ws = (char*)d_ws;
    size_t off = 0;
    auto take = [&](size_t bytes) -> void* {
        void* p = ws + off;
        off = (off + bytes + 255) & ~(size_t)255;
        return p;
    };
    int* counts = (int*)take((size_t)NN * 4);
    int* cursor = (int*)take((size_t)NN * 4);
    int* offs = (int*)take((size_t)(NN + 1) * 4);
    int* bsum = (int*)take(4096);
    int* cols_s = (int*)take((size_t)NE * 4);
    float* vals_s = (float*)take((size_t)NE * 4);
    _Float16* Xa = (_Float16*)take((size_t)MPAD * DD * 2);
    _Float16* Xb = (_Float16*)take((size_t)MPAD * DD * 2);
    _Float16* Wt = (_Float16*)take((size_t)4 * DD * DD * 2);
    float* Y5 = (float*)take((size_t)NN * KC * 4);

    hipMemsetAsync(counts, 0, (size_t)NN * 4, stream);
    hipMemsetAsync(cursor, 0, (size_t)NN * 4, stream);

    k_hist<<<(NE + 255) / 256, 256, 0, stream>>>(erow, counts);
    const int nsb = (NN + 1023) / 1024;  // 98
    k_scan1<<<nsb, 256, 0, stream>>>(counts, offs, bsum);
    k_scan2<<<1, 64, 0, stream>>>(bsum, nsb);
    k_scan3<<<(NN + 256) / 256, 256, 0, stream>>>(offs, bsum);
    k_fill<<<(NE + 255) / 256, 256, 0, stream>>>(erow, ecol, evals, offs, cursor, cols_s, vals_s);

    k_cvtX<<<(NN * DD / 8 + 255) / 256, 256, 0, stream>>>(enc, Xa);
    k_cvtW<<<dim3(8, 8, 4), 256, 0, stream>>>(W1, W2, W3, W4, Wt);

    const int gb = MPAD / 128;  // 782
    const int rb = NN / 4;      // 25000

    k_gemm_h<<<gb, 512, 0, stream>>>(Xa, Wt + 0 * DD * DD, Xb);
    k_spmm_h<<<rb, 256, 0, stream>>>(offs, cols_s, vals_s, Xb, tra1, Xa);

    k_gemm_h<<<gb, 512, 0, stream>>>(Xa, Wt + 1 * DD * DD, Xb);
    k_spmm_h<<<rb, 256, 0, stream>>>(offs, cols_s, vals_s, Xb, tra2, Xa);

    k_gemm_h<<<gb, 512, 0, stream>>>(Xa, Wt + 2 * DD * DD, Xb);
    k_spmm_h<<<rb, 256, 0, stream>>>(offs, cols_s, vals_s, Xb, tra3, Xa);

    k_gemm_h<<<gb, 512, 0, stream>>>(Xa, Wt + 3 * DD * DD, Xb);
    k_spmm_h<<<rb, 256, 0, stream>>>(offs, cols_s, vals_s, Xb, z, Xa);

    k_gemm5<<<rb, 256, 0, stream>>>(Xa, W5, Y5);
    k_sm5<<<rb, 256, 0, stream>>>(offs, cols_s, vals_s, Y5, out);
    k_q<<<rb, 256, 0, stream>>>(z, cluster, out);
}

// Round 3
// 1496.955 us; speedup vs baseline: 2.0308x; 1.0375x over previous
//
#include <hip/hip_runtime.h>

#define NN 100000
#define NE 3200000
#define DD 256
#define KC 4
#define MPAD 100096  // 782 * 128

typedef _Float16 f16x8 __attribute__((ext_vector_type(8)));
typedef _Float16 f16x4 __attribute__((ext_vector_type(4)));
typedef float f32x4 __attribute__((ext_vector_type(4)));

// ---------------------------------------------------------------- CSR build

__global__ __launch_bounds__(256) void k_hist(const int* __restrict__ row,
                                              int* __restrict__ counts) {
    int e = blockIdx.x * 256 + threadIdx.x;
    if (e < NE) atomicAdd(&counts[row[e]], 1);
}

__global__ __launch_bounds__(256) void k_scan1(const int* __restrict__ counts,
                                               int* __restrict__ offs,
                                               int* __restrict__ bsum) {
    __shared__ int s[256];
    const int t = threadIdx.x;
    const int base = blockIdx.x * 1024 + t * 4;
    int v[4];
    int sum = 0;
#pragma unroll
    for (int i = 0; i < 4; ++i) {
        v[i] = (base + i < NN) ? counts[base + i] : 0;
        sum += v[i];
    }
    s[t] = sum;
    __syncthreads();
    for (int off = 1; off < 256; off <<= 1) {
        int x = (t >= off) ? s[t - off] : 0;
        __syncthreads();
        s[t] += x;
        __syncthreads();
    }
    int run = (t > 0) ? s[t - 1] : 0;
#pragma unroll
    for (int i = 0; i < 4; ++i) {
        if (base + i < NN) offs[base + i] = run;
        run += v[i];
    }
    if (t == 255) bsum[blockIdx.x] = s[255];
}

__global__ void k_scan2(int* __restrict__ bsum, int nb) {
    if (threadIdx.x == 0 && blockIdx.x == 0) {
        int run = 0;
        for (int i = 0; i < nb; ++i) {
            int c = bsum[i];
            bsum[i] = run;
            run += c;
        }
    }
}

__global__ __launch_bounds__(256) void k_scan3(int* __restrict__ offs,
                                               const int* __restrict__ bsum) {
    int i = blockIdx.x * 256 + threadIdx.x;
    if (i < NN)
        offs[i] += bsum[i >> 10];
    else if (i == NN)
        offs[NN] = NE;
}

__global__ __launch_bounds__(256) void k_fill(const int* __restrict__ row,
                                              const int* __restrict__ col,
                                              const float* __restrict__ val,
                                              const int* __restrict__ offs,
                                              int* __restrict__ cursor,
                                              int* __restrict__ cols_s,
                                              float* __restrict__ vals_s) {
    int e = blockIdx.x * 256 + threadIdx.x;
    if (e >= NE) return;
    int r = row[e];
    int p = offs[r] + atomicAdd(&cursor[r], 1);
    cols_s[p] = col[e];
    vals_s[p] = val[e];
}

// ---------------------------------------------------------------- fp16 converts

__global__ __launch_bounds__(256) void k_cvtX(const float* __restrict__ in,
                                              _Float16* __restrict__ out) {
    const size_t base = ((size_t)blockIdx.x * 256 + threadIdx.x) * 8;
    if (base >= (size_t)NN * DD) return;
    f32x4 v0 = __builtin_nontemporal_load(reinterpret_cast<const f32x4*>(in + base));
    f32x4 v1 = __builtin_nontemporal_load(reinterpret_cast<const f32x4*>(in + base + 4));
    f16x8 o;
    o[0] = (_Float16)v0[0]; o[1] = (_Float16)v0[1]; o[2] = (_Float16)v0[2]; o[3] = (_Float16)v0[3];
    o[4] = (_Float16)v1[0]; o[5] = (_Float16)v1[1]; o[6] = (_Float16)v1[2]; o[7] = (_Float16)v1[3];
    *reinterpret_cast<f16x8*>(out + base) = o;
}

__global__ __launch_bounds__(256) void k_cvtW(const float* __restrict__ W1,
                                              const float* __restrict__ W2,
                                              const float* __restrict__ W3,
                                              const float* __restrict__ W4,
                                              _Float16* __restrict__ Wt) {
    __shared__ float s[32][33];
    const float* W = (blockIdx.z == 0) ? W1 : (blockIdx.z == 1) ? W2 : (blockIdx.z == 2) ? W3 : W4;
    _Float16* o = Wt + (size_t)blockIdx.z * DD * DD;
    const int bk = blockIdx.x * 32;
    const int bn = blockIdx.y * 32;
    const int tx = threadIdx.x & 31, ty = threadIdx.x >> 5;
    for (int r = ty; r < 32; r += 8) s[r][tx] = W[(size_t)(bk + r) * DD + bn + tx];
    __syncthreads();
    for (int r = ty; r < 32; r += 8) o[(size_t)(bn + r) * DD + bk + tx] = (_Float16)s[tx][r];
}

// ---------------------------------------------------------------- GEMM fp16 MFMA

__device__ __forceinline__ void load_lds16(const void* g, void* l) {
    __builtin_amdgcn_global_load_lds((const __attribute__((address_space(1))) void*)g,
                                     (__attribute__((address_space(3))) void*)l, 16, 0, 0);
}

__global__ __launch_bounds__(512, 4) void k_gemm_h(const _Float16* __restrict__ X,
                                                   const _Float16* __restrict__ Wt,
                                                   _Float16* __restrict__ Y) {
    __shared__ __align__(16) char lds[49152];  // A[2][8192] | B[2][16384]
    char* const Albase = lds;
    char* const Blbase = lds + 16384;

    const int tid = threadIdx.x;
    const int lane = tid & 63;
    const int wid = tid >> 6;
    const int wr = wid >> 2;
    const int wc = wid & 3;
    const int bm = blockIdx.x * 128;

    const int aoffl = wid * 1024 + lane * 16;
    const int arw = aoffl >> 6;
    const int acb = (aoffl & 63) ^ (((arw >> 1) & 3) << 4);
    const char* const Asrc0 = (const char*)X + ((size_t)(bm + arw) * DD) * 2 + acb;
    char* const Adst0 = Albase + wid * 1024;

    const int boffl0 = wid * 1024 + lane * 16;
    const int brw0 = boffl0 >> 6;
    const int bcb0 = (boffl0 & 63) ^ (((brw0 >> 1) & 3) << 4);
    const char* const Bsrc0 = (const char*)Wt + ((size_t)brw0 * DD) * 2 + bcb0;
    const int boffl1 = 8192 + wid * 1024 + lane * 16;
    const int brw1 = boffl1 >> 6;
    const int bcb1 = (boffl1 & 63) ^ (((brw1 >> 1) & 3) << 4);
    const char* const Bsrc1 = (const char*)Wt + ((size_t)brw1 * DD) * 2 + bcb1;
    char* const Bdst0 = Blbase + wid * 1024;
    char* const Bdst1 = Blbase + 8192 + wid * 1024;

    int aro[4], bro[4];
#pragma unroll
    for (int m = 0; m < 4; ++m) {
        const int r = wr * 64 + m * 16 + (lane & 15);
        aro[m] = r * 64 + ((((lane >> 4) * 16)) ^ (((r >> 1) & 3) << 4));
    }
#pragma unroll
    for (int n = 0; n < 4; ++n) {
        const int r = wc * 64 + n * 16 + (lane & 15);
        bro[n] = r * 64 + ((((lane >> 4) * 16)) ^ (((r >> 1) & 3) << 4));
    }

    f32x4 acc[4][4];
#pragma unroll
    for (int m = 0; m < 4; ++m)
#pragma unroll
        for (int n = 0; n < 4; ++n) acc[m][n] = (f32x4){0.f, 0.f, 0.f, 0.f};

    load_lds16(Asrc0, Adst0);
    load_lds16(Bsrc0, Bdst0);
    load_lds16(Bsrc1, Bdst1);
    __syncthreads();

    for (int kt = 0; kt < 8; ++kt) {
        const int cur = kt & 1;
        if (kt < 7) {
            const size_t kb = (size_t)(kt + 1) * 32 * 2;
            load_lds16(Asrc0 + kb, Adst0 + (cur ^ 1) * 8192);
            load_lds16(Bsrc0 + kb, Bdst0 + (cur ^ 1) * 16384);
            load_lds16(Bsrc1 + kb, Bdst1 + (cur ^ 1) * 16384);
        }
        const char* Ab = Albase + cur * 8192;
        const char* Bb = Blbase + cur * 16384;
        f16x8 af[4], bf[4];
#pragma unroll
        for (int m = 0; m < 4; ++m) af[m] = *reinterpret_cast<const f16x8*>(Ab + aro[m]);
#pragma unroll
        for (int n = 0; n < 4; ++n) bf[n] = *reinterpret_cast<const f16x8*>(Bb + bro[n]);
#pragma unroll
        for (int m = 0; m < 4; ++m)
#pragma unroll
            for (int n = 0; n < 4; ++n)
                acc[m][n] = __builtin_amdgcn_mfma_f32_16x16x32_f16(af[m], bf[n], acc[m][n], 0, 0, 0);
        __syncthreads();
    }

#pragma unroll
    for (int m = 0; m < 4; ++m) {
        const int row = bm + wr * 64 + m * 16 + (lane >> 4) * 4;
#pragma unroll
        for (int n = 0; n < 4; ++n) {
            const int col = wc * 64 + n * 16 + (lane & 15);
#pragma unroll
            for (int j = 0; j < 4; ++j)
                Y[(size_t)(row + j) * DD + col] = (_Float16)acc[m][n][j];
        }
    }
}

// ---------------------------------------------------------------- SpMM fp16
// Two 32-lane halves per wave process alternate edges; lane covers 8 dims (16B).

__global__ __launch_bounds__(256) void k_spmm_h(const int* __restrict__ offs,
                                                const int* __restrict__ cols,
                                                const float* __restrict__ vals,
                                                const _Float16* __restrict__ Y,
                                                const float* __restrict__ blend,
                                                _Float16* __restrict__ Xout) {
    const int row = blockIdx.x * 4 + (threadIdx.x >> 6);
    if (row >= NN) return;
    const int lane = threadIdx.x & 63;
    const int half = lane >> 5;
    const int sub = lane & 31;
    const int e0 = offs[row], e1 = offs[row + 1];
    float acc[8] = {};
    int e = e0 + half;
    for (; e + 6 < e1; e += 8) {
        const int c0 = cols[e], c1 = cols[e + 2], c2 = cols[e + 4], c3 = cols[e + 6];
        const float v0 = vals[e], v1 = vals[e + 2], v2 = vals[e + 4], v3 = vals[e + 6];
        const f16x8 y0 = *reinterpret_cast<const f16x8*>(Y + (size_t)c0 * DD + sub * 8);
        const f16x8 y1 = *reinterpret_cast<const f16x8*>(Y + (size_t)c1 * DD + sub * 8);
        const f16x8 y2 = *reinterpret_cast<const f16x8*>(Y + (size_t)c2 * DD + sub * 8);
        const f16x8 y3 = *reinterpret_cast<const f16x8*>(Y + (size_t)c3 * DD + sub * 8);
#pragma unroll
        for (int j = 0; j < 8; ++j)
            acc[j] += v0 * (float)y0[j] + v1 * (float)y1[j] + v2 * (float)y2[j] + v3 * (float)y3[j];
    }
    for (; e < e1; e += 2) {
        const float v = vals[e];
        const f16x8 y = *reinterpret_cast<const f16x8*>(Y + (size_t)cols[e] * DD + sub * 8);
#pragma unroll
        for (int j = 0; j < 8; ++j) acc[j] += v * (float)y[j];
    }
#pragma unroll
    for (int j = 0; j < 8; ++j) acc[j] += __shfl_xor(acc[j], 32);
    if (half == 0) {
        const size_t bi = (size_t)row * DD + sub * 8;
        const f32x4 t0 = __builtin_nontemporal_load(reinterpret_cast<const f32x4*>(blend + bi));
        const f32x4 t1 = __builtin_nontemporal_load(reinterpret_cast<const f32x4*>(blend + bi + 4));
        f16x8 o;
        o[0] = (_Float16)(0.5f * fmaxf(acc[0], 0.f) + 0.5f * t0[0]);
        o[1] = (_Float16)(0.5f * fmaxf(acc[1], 0.f) + 0.5f * t0[1]);
        o[2] = (_Float16)(0.5f * fmaxf(acc[2], 0.f) + 0.5f * t0[2]);
        o[3] = (_Float16)(0.5f * fmaxf(acc[3], 0.f) + 0.5f * t0[3]);
        o[4] = (_Float16)(0.5f * fmaxf(acc[4], 0.f) + 0.5f * t1[0]);
        o[5] = (_Float16)(0.5f * fmaxf(acc[5], 0.f) + 0.5f * t1[1]);
        o[6] = (_Float16)(0.5f * fmaxf(acc[6], 0.f) + 0.5f * t1[2]);
        o[7] = (_Float16)(0.5f * fmaxf(acc[7], 0.f) + 0.5f * t1[3]);
        *reinterpret_cast<f16x8*>(Xout + bi) = o;
    }
}

// Last layer: fused agg -> blend(z) -> Y5 = blended @ W5 (fp32) and q columns.
__global__ __launch_bounds__(256) void k_spmm_last(const int* __restrict__ offs,
                                                   const int* __restrict__ cols,
                                                   const float* __restrict__ vals,
                                                   const _Float16* __restrict__ Y,
                                                   const float* __restrict__ z,
                                                   const float* __restrict__ W5,
                                                   const float* __restrict__ cl,
                                                   float* __restrict__ Y5,
                                                   float* __restrict__ out) {
    const int row = blockIdx.x * 4 + (threadIdx.x >> 6);
    if (row >= NN) return;
    const int lane = threadIdx.x & 63;
    const int half = lane >> 5;
    const int sub = lane & 31;
    const int e0 = offs[row], e1 = offs[row + 1];
    float acc[8] = {};
    int e = e0 + half;
    for (; e + 6 < e1; e += 8) {
        const int c0 = cols[e], c1 = cols[e + 2], c2 = cols[e + 4], c3 = cols[e + 6];
        const float v0 = vals[e], v1 = vals[e + 2], v2 = vals[e + 4], v3 = vals[e + 6];
        const f16x8 y0 = *reinterpret_cast<const f16x8*>(Y + (size_t)c0 * DD + sub * 8);
        const f16x8 y1 = *reinterpret_cast<const f16x8*>(Y + (size_t)c1 * DD + sub * 8);
        const f16x8 y2 = *reinterpret_cast<const f16x8*>(Y + (size_t)c2 * DD + sub * 8);
        const f16x8 y3 = *reinterpret_cast<const f16x8*>(Y + (size_t)c3 * DD + sub * 8);
#pragma unroll
        for (int j = 0; j < 8; ++j)
            acc[j] += v0 * (float)y0[j] + v1 * (float)y1[j] + v2 * (float)y2[j] + v3 * (float)y3[j];
    }
    for (; e < e1; e += 2) {
        const float v = vals[e];
        const f16x8 y = *reinterpret_cast<const f16x8*>(Y + (size_t)cols[e] * DD + sub * 8);
#pragma unroll
        for (int j = 0; j < 8; ++j) acc[j] += v * (float)y[j];
    }
#pragma unroll
    for (int j = 0; j < 8; ++j) acc[j] += __shfl_xor(acc[j], 32);
    if (half == 0) {
        const size_t bi = (size_t)row * DD + sub * 8;
        const f32x4 z0 = __builtin_nontemporal_load(reinterpret_cast<const f32x4*>(z + bi));
        const f32x4 z1 = __builtin_nontemporal_load(reinterpret_cast<const f32x4*>(z + bi + 4));
        float zb[8] = {z0[0], z0[1], z0[2], z0[3], z1[0], z1[1], z1[2], z1[3]};
        float b[8];
#pragma unroll
        for (int j = 0; j < 8; ++j) b[j] = 0.5f * fmaxf(acc[j], 0.f) + 0.5f * zb[j];

        float p[4] = {0.f, 0.f, 0.f, 0.f};
        float zz = 0.f;
#pragma unroll
        for (int j = 0; j < 8; ++j) {
            const int d = sub * 8 + j;
            const f32x4 w = *reinterpret_cast<const f32x4*>(W5 + (size_t)d * KC);
            p[0] += b[j] * w[0];
            p[1] += b[j] * w[1];
            p[2] += b[j] * w[2];
            p[3] += b[j] * w[3];
            zz += zb[j] * zb[j];
        }
        float dot[4] = {0.f, 0.f, 0.f, 0.f}, cc[4] = {0.f, 0.f, 0.f, 0.f};
#pragma unroll
        for (int c2 = 0; c2 < 4; ++c2) {
            const f32x4 c40 = *reinterpret_cast<const f32x4*>(cl + (size_t)c2 * DD + sub * 8);
            const f32x4 c41 = *reinterpret_cast<const f32x4*>(cl + (size_t)c2 * DD + sub * 8 + 4);
            dot[c2] += zb[0] * c40[0] + zb[1] * c40[1] + zb[2] * c40[2] + zb[3] * c40[3] +
                       zb[4] * c41[0] + zb[5] * c41[1] + zb[6] * c41[2] + zb[7] * c41[3];
            cc[c2] += c40[0] * c40[0] + c40[1] * c40[1] + c40[2] * c40[2] + c40[3] * c40[3] +
                      c41[0] * c41[0] + c41[1] * c41[1] + c41[2] * c41[2] + c41[3] * c41[3];
        }
        // reduce 13 scalars over the 32 active lanes
#pragma unroll
        for (int o = 16; o; o >>= 1) {
            zz += __shfl_xor(zz, o);
#pragma unroll
            for (int c2 = 0; c2 < 4; ++c2) {
                p[c2] += __shfl_xor(p[c2], o);
                dot[c2] += __shfl_xor(dot[c2], o);
                cc[c2] += __shfl_xor(cc[c2], o);
            }
        }
        if (sub == 0) {
            *reinterpret_cast<f32x4*>(Y5 + (size_t)row * KC) = (f32x4){p[0], p[1], p[2], p[3]};
            float q[4], s = 0.f;
#pragma unroll
            for (int c2 = 0; c2 < 4; ++c2) {
                const float d2 = zz - 2.f * dot[c2] + cc[c2];
                q[c2] = 1.f / (1.f + d2);
                s += q[c2];
            }
            const float inv = 1.f / s;
            *reinterpret_cast<f32x4*>(out + (size_t)row * 8 + 4) =
                (f32x4){q[0] * inv, q[1] * inv, q[2] * inv, q[3] * inv};
        }
    }
}

// ---------------------------------------------------------------- softmax tail

__device__ inline float wred(float v) {
#pragma unroll
    for (int o = 32; o; o >>= 1) v += __shfl_down(v, o);
    return v;
}

__global__ __launch_bounds__(256) void k_sm5(const int* __restrict__ offs,
                                             const int* __restrict__ cols,
                                             const float* __restrict__ vals,
                                             const float* __restrict__ Y5,
                                             float* __restrict__ out) {
    const int row = blockIdx.x * 4 + (threadIdx.x >> 6);
    if (row >= NN) return;
    const int lane = threadIdx.x & 63;
    const int e0 = offs[row], e1 = offs[row + 1];
    float ax = 0.f, ay = 0.f, az = 0.f, aw = 0.f;
    for (int e = e0 + lane; e < e1; e += 64) {
        const float v = vals[e];
        const f32x4 y = *reinterpret_cast<const f32x4*>(Y5 + (size_t)cols[e] * KC);
        ax += v * y[0];
        ay += v * y[1];
        az += v * y[2];
        aw += v * y[3];
    }
    ax = wred(ax);
    ay = wred(ay);
    az = wred(az);
    aw = wred(aw);
    if (lane == 0) {
        float m = fmaxf(fmaxf(ax, ay), fmaxf(az, aw));
        float ex = __expf(ax - m), ey = __expf(ay - m), ez = __expf(az - m), ew = __expf(aw - m);
        float inv = 1.f / (ex + ey + ez + ew);
        *reinterpret_cast<f32x4*>(out + (size_t)row * 8) =
            (f32x4){ex * inv, ey * inv, ez * inv, ew * inv};
    }
}

// ---------------------------------------------------------------- launch

extern "C" void kernel_launch(void* const* d_in, const int* in_sizes, int n_in,
                              void* d_out, int out_size, void* d_ws, size_t ws_size,
                              hipStream_t stream) {
    const float* enc = (const float*)d_in[0];
    const float* tra1 = (const float*)d_in[1];
    const float* tra2 = (const float*)d_in[2];
    const float* tra3 = (const float*)d_in[3];
    const float* z = (const float*)d_in[4];
    const int* erow = (const int*)d_in[5];
    const int* ecol = (const int*)d_in[6];
    const float* evals = (const float*)d_in[7];
    const float* W1 = (const float*)d_in[8];
    const float* W2 = (const float*)d_in[9];
    const float* W3 = (const float*)d_in[10];
    const float* W4 = (const float*)d_in[11];
    const float* W5 = (const float*)d_in[12];
    const float* cluster = (const float*)d_in[13];
    float* out = (float*)d_out;

    char* ws = (char*)d_ws;
    size_t off = 0;
    auto take = [&](size_t bytes) -> void* {
        void* p = ws + off;
        off = (off + bytes + 255) & ~(size_t)255;
        return p;
    };
    int* counts = (int*)take((size_t)NN * 4);
    int* cursor = (int*)take((size_t)NN * 4);
    int* offs = (int*)take((size_t)(NN + 1) * 4);
    int* bsum = (int*)take(4096);
    int* cols_s = (int*)take((size_t)NE * 4);
    float* vals_s = (float*)take((size_t)NE * 4);
    _Float16* Xa = (_Float16*)take((size_t)MPAD * DD * 2);
    _Float16* Xb = (_Float16*)take((size_t)MPAD * DD * 2);
    _Float16* Wt = (_Float16*)take((size_t)4 * DD * DD * 2);
    float* Y5 = (float*)take((size_t)NN * KC * 4);

    hipMemsetAsync(counts, 0, (size_t)NN * 4, stream);
    hipMemsetAsync(cursor, 0, (size_t)NN * 4, stream);

    k_hist<<<(NE + 255) / 256, 256, 0, stream>>>(erow, counts);
    const int nsb = (NN + 1023) / 1024;  // 98
    k_scan1<<<nsb, 256, 0, stream>>>(counts, offs, bsum);
    k_scan2<<<1, 64, 0, stream>>>(bsum, nsb);
    k_scan3<<<(NN + 256) / 256, 256, 0, stream>>>(offs, bsum);
    k_fill<<<(NE + 255) / 256, 256, 0, stream>>>(erow, ecol, evals, offs, cursor, cols_s, vals_s);

    k_cvtX<<<(NN * DD / 8 + 255) / 256, 256, 0, stream>>>(enc, Xa);
    k_cvtW<<<dim3(8, 8, 4), 256, 0, stream>>>(W1, W2, W3, W4, Wt);

    const int gb = MPAD / 128;  // 782
    const int rb = NN / 4;      // 25000

    k_gemm_h<<<gb, 512, 0, stream>>>(Xa, Wt + 0 * DD * DD, Xb);
    k_spmm_h<<<rb, 256, 0, stream>>>(offs, cols_s, vals_s, Xb, tra1, Xa);

    k_gemm_h<<<gb, 512, 0, stream>>>(Xa, Wt + 1 * DD * DD, Xb);
    k_spmm_h<<<rb, 256, 0, stream>>>(offs, cols_s, vals_s, Xb, tra2, Xa);

    k_gemm_h<<<gb, 512, 0, stream>>>(Xa, Wt + 2 * DD * DD, Xb);
    k_spmm_h<<<rb, 256, 0, stream>>>(offs, cols_s, vals_s, Xb, tra3, Xa);

    k_gemm_h<<<gb, 512, 0, stream>>>(Xa, Wt + 3 * DD * DD, Xb);
    k_spmm_last<<<rb, 256, 0, stream>>>(offs, cols_s, vals_s, Xb, z, W5, cluster, Y5, out);

    k_sm5<<<rb, 256, 0, stream>>>(offs, cols_s, vals_s, Y5, out);
}

// Round 4
// 1437.204 us; speedup vs baseline: 2.1152x; 1.0416x over previous
//
#include <hip/hip_runtime.h>

#define NN 100000
#define NE 3200000
#define DD 256
#define KC 4
#define MPAD 100096  // 782 * 128

typedef _Float16 f16x8 __attribute__((ext_vector_type(8)));
typedef _Float16 f16x4 __attribute__((ext_vector_type(4)));
typedef float f32x4 __attribute__((ext_vector_type(4)));

// ---------------------------------------------------------------- CSR build

__global__ __launch_bounds__(256) void k_hist(const int* __restrict__ row,
                                              int* __restrict__ counts) {
    int e = blockIdx.x * 256 + threadIdx.x;
    if (e < NE) atomicAdd(&counts[row[e]], 1);
}

__global__ __launch_bounds__(256) void k_scan1(const int* __restrict__ counts,
                                               int* __restrict__ offs,
                                               int* __restrict__ bsum) {
    __shared__ int s[256];
    const int t = threadIdx.x;
    const int base = blockIdx.x * 1024 + t * 4;
    int v[4];
    int sum = 0;
#pragma unroll
    for (int i = 0; i < 4; ++i) {
        v[i] = (base + i < NN) ? counts[base + i] : 0;
        sum += v[i];
    }
    s[t] = sum;
    __syncthreads();
    for (int off = 1; off < 256; off <<= 1) {
        int x = (t >= off) ? s[t - off] : 0;
        __syncthreads();
        s[t] += x;
        __syncthreads();
    }
    int run = (t > 0) ? s[t - 1] : 0;
#pragma unroll
    for (int i = 0; i < 4; ++i) {
        if (base + i < NN) offs[base + i] = run;
        run += v[i];
    }
    if (t == 255) bsum[blockIdx.x] = s[255];
}

__global__ void k_scan2(int* __restrict__ bsum, int nb) {
    if (threadIdx.x == 0 && blockIdx.x == 0) {
        int run = 0;
        for (int i = 0; i < nb; ++i) {
            int c = bsum[i];
            bsum[i] = run;
            run += c;
        }
    }
}

__global__ __launch_bounds__(256) void k_scan3(int* __restrict__ offs,
                                               const int* __restrict__ bsum) {
    int i = blockIdx.x * 256 + threadIdx.x;
    if (i < NN)
        offs[i] += bsum[i >> 10];
    else if (i == NN)
        offs[NN] = NE;
}

// edge record: .x = col, .y = bit-pattern of val  (one 8B line-touch per edge)
__global__ __launch_bounds__(256) void k_fill(const int* __restrict__ row,
                                              const int* __restrict__ col,
                                              const float* __restrict__ val,
                                              const int* __restrict__ offs,
                                              int* __restrict__ cursor,
                                              int2* __restrict__ edges) {
    int e = blockIdx.x * 256 + threadIdx.x;
    if (e >= NE) return;
    int r = row[e];
    int p = offs[r] + atomicAdd(&cursor[r], 1);
    int2 ev;
    ev.x = col[e];
    ev.y = __float_as_int(val[e]);
    edges[p] = ev;
}

// ---------------------------------------------------------------- fp16 converts

__global__ __launch_bounds__(256) void k_cvtX(const float* __restrict__ in,
                                              _Float16* __restrict__ out) {
    const size_t base = ((size_t)blockIdx.x * 256 + threadIdx.x) * 8;
    if (base >= (size_t)NN * DD) return;
    f32x4 v0 = __builtin_nontemporal_load(reinterpret_cast<const f32x4*>(in + base));
    f32x4 v1 = __builtin_nontemporal_load(reinterpret_cast<const f32x4*>(in + base + 4));
    f16x8 o;
    o[0] = (_Float16)v0[0]; o[1] = (_Float16)v0[1]; o[2] = (_Float16)v0[2]; o[3] = (_Float16)v0[3];
    o[4] = (_Float16)v1[0]; o[5] = (_Float16)v1[1]; o[6] = (_Float16)v1[2]; o[7] = (_Float16)v1[3];
    *reinterpret_cast<f16x8*>(out + base) = o;
}

__global__ __launch_bounds__(256) void k_cvtW(const float* __restrict__ W1,
                                              const float* __restrict__ W2,
                                              const float* __restrict__ W3,
                                              const float* __restrict__ W4,
                                              _Float16* __restrict__ Wt) {
    __shared__ float s[32][33];
    const float* W = (blockIdx.z == 0) ? W1 : (blockIdx.z == 1) ? W2 : (blockIdx.z == 2) ? W3 : W4;
    _Float16* o = Wt + (size_t)blockIdx.z * DD * DD;
    const int bk = blockIdx.x * 32;
    const int bn = blockIdx.y * 32;
    const int tx = threadIdx.x & 31, ty = threadIdx.x >> 5;
    for (int r = ty; r < 32; r += 8) s[r][tx] = W[(size_t)(bk + r) * DD + bn + tx];
    __syncthreads();
    for (int r = ty; r < 32; r += 8) o[(size_t)(bn + r) * DD + bk + tx] = (_Float16)s[tx][r];
}

// ---------------------------------------------------------------- GEMM fp16 MFMA

__device__ __forceinline__ void load_lds16(const void* g, void* l) {
    __builtin_amdgcn_global_load_lds((const __attribute__((address_space(1))) void*)g,
                                     (__attribute__((address_space(3))) void*)l, 16, 0, 0);
}

__global__ __launch_bounds__(512, 4) void k_gemm_h(const _Float16* __restrict__ X,
                                                   const _Float16* __restrict__ Wt,
                                                   _Float16* __restrict__ Y) {
    __shared__ __align__(16) char lds[49152];  // A[2][8192] | B[2][16384]
    char* const Albase = lds;
    char* const Blbase = lds + 16384;

    const int tid = threadIdx.x;
    const int lane = tid & 63;
    const int wid = tid >> 6;
    const int wr = wid >> 2;
    const int wc = wid & 3;
    const int bm = blockIdx.x * 128;

    const int aoffl = wid * 1024 + lane * 16;
    const int arw = aoffl >> 6;
    const int acb = (aoffl & 63) ^ (((arw >> 1) & 3) << 4);
    const char* const Asrc0 = (const char*)X + ((size_t)(bm + arw) * DD) * 2 + acb;
    char* const Adst0 = Albase + wid * 1024;

    const int boffl0 = wid * 1024 + lane * 16;
    const int brw0 = boffl0 >> 6;
    const int bcb0 = (boffl0 & 63) ^ (((brw0 >> 1) & 3) << 4);
    const char* const Bsrc0 = (const char*)Wt + ((size_t)brw0 * DD) * 2 + bcb0;
    const int boffl1 = 8192 + wid * 1024 + lane * 16;
    const int brw1 = boffl1 >> 6;
    const int bcb1 = (boffl1 & 63) ^ (((brw1 >> 1) & 3) << 4);
    const char* const Bsrc1 = (const char*)Wt + ((size_t)brw1 * DD) * 2 + bcb1;
    char* const Bdst0 = Blbase + wid * 1024;
    char* const Bdst1 = Blbase + 8192 + wid * 1024;

    int aro[4], bro[4];
#pragma unroll
    for (int m = 0; m < 4; ++m) {
        const int r = wr * 64 + m * 16 + (lane & 15);
        aro[m] = r * 64 + ((((lane >> 4) * 16)) ^ (((r >> 1) & 3) << 4));
    }
#pragma unroll
    for (int n = 0; n < 4; ++n) {
        const int r = wc * 64 + n * 16 + (lane & 15);
        bro[n] = r * 64 + ((((lane >> 4) * 16)) ^ (((r >> 1) & 3) << 4));
    }

    f32x4 acc[4][4];
#pragma unroll
    for (int m = 0; m < 4; ++m)
#pragma unroll
        for (int n = 0; n < 4; ++n) acc[m][n] = (f32x4){0.f, 0.f, 0.f, 0.f};

    load_lds16(Asrc0, Adst0);
    load_lds16(Bsrc0, Bdst0);
    load_lds16(Bsrc1, Bdst1);
    __syncthreads();

    for (int kt = 0; kt < 8; ++kt) {
        const int cur = kt & 1;
        if (kt < 7) {
            const size_t kb = (size_t)(kt + 1) * 32 * 2;
            load_lds16(Asrc0 + kb, Adst0 + (cur ^ 1) * 8192);
            load_lds16(Bsrc0 + kb, Bdst0 + (cur ^ 1) * 16384);
            load_lds16(Bsrc1 + kb, Bdst1 + (cur ^ 1) * 16384);
        }
        const char* Ab = Albase + cur * 8192;
        const char* Bb = Blbase + cur * 16384;
        f16x8 af[4], bf[4];
#pragma unroll
        for (int m = 0; m < 4; ++m) af[m] = *reinterpret_cast<const f16x8*>(Ab + aro[m]);
#pragma unroll
        for (int n = 0; n < 4; ++n) bf[n] = *reinterpret_cast<const f16x8*>(Bb + bro[n]);
#pragma unroll
        for (int m = 0; m < 4; ++m)
#pragma unroll
            for (int n = 0; n < 4; ++n)
                acc[m][n] = __builtin_amdgcn_mfma_f32_16x16x32_f16(af[m], bf[n], acc[m][n], 0, 0, 0);
        __syncthreads();
    }

#pragma unroll
    for (int m = 0; m < 4; ++m) {
        const int row = bm + wr * 64 + m * 16 + (lane >> 4) * 4;
#pragma unroll
        for (int n = 0; n < 4; ++n) {
            const int col = wc * 64 + n * 16 + (lane & 15);
#pragma unroll
            for (int j = 0; j < 4; ++j)
                Y[(size_t)(row + j) * DD + col] = (_Float16)acc[m][n][j];
        }
    }
}

// ---------------------------------------------------------------- SpMM fp16

__global__ __launch_bounds__(256) void k_spmm_h(const int* __restrict__ offs,
                                                const int2* __restrict__ edges,
                                                const _Float16* __restrict__ Y,
                                                const float* __restrict__ blend,
                                                _Float16* __restrict__ Xout) {
    const int row = blockIdx.x * 4 + (threadIdx.x >> 6);
    if (row >= NN) return;
    const int lane = threadIdx.x & 63;
    const int half = lane >> 5;
    const int sub = lane & 31;
    const int e0 = offs[row], e1 = offs[row + 1];
    float acc[8] = {};
    int e = e0 + half;
    for (; e + 6 < e1; e += 8) {
        const int2 ev0 = edges[e], ev1 = edges[e + 2], ev2 = edges[e + 4], ev3 = edges[e + 6];
        const float v0 = __int_as_float(ev0.y), v1 = __int_as_float(ev1.y);
        const float v2 = __int_as_float(ev2.y), v3 = __int_as_float(ev3.y);
        const f16x8 y0 = *reinterpret_cast<const f16x8*>(Y + (size_t)ev0.x * DD + sub * 8);
        const f16x8 y1 = *reinterpret_cast<const f16x8*>(Y + (size_t)ev1.x * DD + sub * 8);
        const f16x8 y2 = *reinterpret_cast<const f16x8*>(Y + (size_t)ev2.x * DD + sub * 8);
        const f16x8 y3 = *reinterpret_cast<const f16x8*>(Y + (size_t)ev3.x * DD + sub * 8);
#pragma unroll
        for (int j = 0; j < 8; ++j)
            acc[j] += v0 * (float)y0[j] + v1 * (float)y1[j] + v2 * (float)y2[j] + v3 * (float)y3[j];
    }
    for (; e < e1; e += 2) {
        const int2 ev = edges[e];
        const float v = __int_as_float(ev.y);
        const f16x8 y = *reinterpret_cast<const f16x8*>(Y + (size_t)ev.x * DD + sub * 8);
#pragma unroll
        for (int j = 0; j < 8; ++j) acc[j] += v * (float)y[j];
    }
#pragma unroll
    for (int j = 0; j < 8; ++j) acc[j] += __shfl_xor(acc[j], 32);
    if (half == 0) {
        const size_t bi = (size_t)row * DD + sub * 8;
        const f32x4 t0 = __builtin_nontemporal_load(reinterpret_cast<const f32x4*>(blend + bi));
        const f32x4 t1 = __builtin_nontemporal_load(reinterpret_cast<const f32x4*>(blend + bi + 4));
        f16x8 o;
        o[0] = (_Float16)(0.5f * fmaxf(acc[0], 0.f) + 0.5f * t0[0]);
        o[1] = (_Float16)(0.5f * fmaxf(acc[1], 0.f) + 0.5f * t0[1]);
        o[2] = (_Float16)(0.5f * fmaxf(acc[2], 0.f) + 0.5f * t0[2]);
        o[3] = (_Float16)(0.5f * fmaxf(acc[3], 0.f) + 0.5f * t0[3]);
        o[4] = (_Float16)(0.5f * fmaxf(acc[4], 0.f) + 0.5f * t1[0]);
        o[5] = (_Float16)(0.5f * fmaxf(acc[5], 0.f) + 0.5f * t1[1]);
        o[6] = (_Float16)(0.5f * fmaxf(acc[6], 0.f) + 0.5f * t1[2]);
        o[7] = (_Float16)(0.5f * fmaxf(acc[7], 0.f) + 0.5f * t1[3]);
        *reinterpret_cast<f16x8*>(Xout + bi) = o;
    }
}

// Last layer: fused agg -> blend(z) -> Y5 = blended @ W5 (fp32) and q columns.
__global__ __launch_bounds__(256) void k_spmm_last(const int* __restrict__ offs,
                                                   const int2* __restrict__ edges,
                                                   const _Float16* __restrict__ Y,
                                                   const float* __restrict__ z,
                                                   const float* __restrict__ W5,
                                                   const float* __restrict__ cl,
                                                   float* __restrict__ Y5,
                                                   float* __restrict__ out) {
    const int row = blockIdx.x * 4 + (threadIdx.x >> 6);
    if (row >= NN) return;
    const int lane = threadIdx.x & 63;
    const int half = lane >> 5;
    const int sub = lane & 31;
    const int e0 = offs[row], e1 = offs[row + 1];
    float acc[8] = {};
    int e = e0 + half;
    for (; e + 6 < e1; e += 8) {
        const int2 ev0 = edges[e], ev1 = edges[e + 2], ev2 = edges[e + 4], ev3 = edges[e + 6];
        const float v0 = __int_as_float(ev0.y), v1 = __int_as_float(ev1.y);
        const float v2 = __int_as_float(ev2.y), v3 = __int_as_float(ev3.y);
        const f16x8 y0 = *reinterpret_cast<const f16x8*>(Y + (size_t)ev0.x * DD + sub * 8);
        const f16x8 y1 = *reinterpret_cast<const f16x8*>(Y + (size_t)ev1.x * DD + sub * 8);
        const f16x8 y2 = *reinterpret_cast<const f16x8*>(Y + (size_t)ev2.x * DD + sub * 8);
        const f16x8 y3 = *reinterpret_cast<const f16x8*>(Y + (size_t)ev3.x * DD + sub * 8);
#pragma unroll
        for (int j = 0; j < 8; ++j)
            acc[j] += v0 * (float)y0[j] + v1 * (float)y1[j] + v2 * (float)y2[j] + v3 * (float)y3[j];
    }
    for (; e < e1; e += 2) {
        const int2 ev = edges[e];
        const float v = __int_as_float(ev.y);
        const f16x8 y = *reinterpret_cast<const f16x8*>(Y + (size_t)ev.x * DD + sub * 8);
#pragma unroll
        for (int j = 0; j < 8; ++j) acc[j] += v * (float)y[j];
    }
#pragma unroll
    for (int j = 0; j < 8; ++j) acc[j] += __shfl_xor(acc[j], 32);
    if (half == 0) {
        const size_t bi = (size_t)row * DD + sub * 8;
        const f32x4 z0 = __builtin_nontemporal_load(reinterpret_cast<const f32x4*>(z + bi));
        const f32x4 z1 = __builtin_nontemporal_load(reinterpret_cast<const f32x4*>(z + bi + 4));
        float zb[8] = {z0[0], z0[1], z0[2], z0[3], z1[0], z1[1], z1[2], z1[3]};
        float b[8];
#pragma unroll
        for (int j = 0; j < 8; ++j) b[j] = 0.5f * fmaxf(acc[j], 0.f) + 0.5f * zb[j];

        float p[4] = {0.f, 0.f, 0.f, 0.f};
        float zz = 0.f;
#pragma unroll
        for (int j = 0; j < 8; ++j) {
            const int d = sub * 8 + j;
            const f32x4 w = *reinterpret_cast<const f32x4*>(W5 + (size_t)d * KC);
            p[0] += b[j] * w[0];
            p[1] += b[j] * w[1];
            p[2] += b[j] * w[2];
            p[3] += b[j] * w[3];
            zz += zb[j] * zb[j];
        }
        float dot[4] = {0.f, 0.f, 0.f, 0.f}, cc[4] = {0.f, 0.f, 0.f, 0.f};
#pragma unroll
        for (int c2 = 0; c2 < 4; ++c2) {
            const f32x4 c40 = *reinterpret_cast<const f32x4*>(cl + (size_t)c2 * DD + sub * 8);
            const f32x4 c41 = *reinterpret_cast<const f32x4*>(cl + (size_t)c2 * DD + sub * 8 + 4);
            dot[c2] += zb[0] * c40[0] + zb[1] * c40[1] + zb[2] * c40[2] + zb[3] * c40[3] +
                       zb[4] * c41[0] + zb[5] * c41[1] + zb[6] * c41[2] + zb[7] * c41[3];
            cc[c2] += c40[0] * c40[0] + c40[1] * c40[1] + c40[2] * c40[2] + c40[3] * c40[3] +
                      c41[0] * c41[0] + c41[1] * c41[1] + c41[2] * c41[2] + c41[3] * c41[3];
        }
#pragma unroll
        for (int o = 16; o; o >>= 1) {
            zz += __shfl_xor(zz, o);
#pragma unroll
            for (int c2 = 0; c2 < 4; ++c2) {
                p[c2] += __shfl_xor(p[c2], o);
                dot[c2] += __shfl_xor(dot[c2], o);
                cc[c2] += __shfl_xor(cc[c2], o);
            }
        }
        if (sub == 0) {
            *reinterpret_cast<f32x4*>(Y5 + (size_t)row * KC) = (f32x4){p[0], p[1], p[2], p[3]};
            float q[4], s = 0.f;
#pragma unroll
            for (int c2 = 0; c2 < 4; ++c2) {
                const float d2 = zz - 2.f * dot[c2] + cc[c2];
                q[c2] = 1.f / (1.f + d2);
                s += q[c2];
            }
            const float inv = 1.f / s;
            *reinterpret_cast<f32x4*>(out + (size_t)row * 8 + 4) =
                (f32x4){q[0] * inv, q[1] * inv, q[2] * inv, q[3] * inv};
        }
    }
}

// ---------------------------------------------------------------- softmax tail

__device__ inline float wred(float v) {
#pragma unroll
    for (int o = 32; o; o >>= 1) v += __shfl_down(v, o);
    return v;
}

__global__ __launch_bounds__(256) void k_sm5(const int* __restrict__ offs,
                                             const int2* __restrict__ edges,
                                             const float* __restrict__ Y5,
                                             float* __restrict__ out) {
    const int row = blockIdx.x * 4 + (threadIdx.x >> 6);
    if (row >= NN) return;
    const int lane = threadIdx.x & 63;
    const int e0 = offs[row], e1 = offs[row + 1];
    float ax = 0.f, ay = 0.f, az = 0.f, aw = 0.f;
    for (int e = e0 + lane; e < e1; e += 64) {
        const int2 ev = edges[e];
        const float v = __int_as_float(ev.y);
        const f32x4 y = *reinterpret_cast<const f32x4*>(Y5 + (size_t)ev.x * KC);
        ax += v * y[0];
        ay += v * y[1];
        az += v * y[2];
        aw += v * y[3];
    }
    ax = wred(ax);
    ay = wred(ay);
    az = wred(az);
    aw = wred(aw);
    if (lane == 0) {
        float m = fmaxf(fmaxf(ax, ay), fmaxf(az, aw));
        float ex = __expf(ax - m), ey = __expf(ay - m), ez = __expf(az - m), ew = __expf(aw - m);
        float inv = 1.f / (ex + ey + ez + ew);
        *reinterpret_cast<f32x4*>(out + (size_t)row * 8) =
            (f32x4){ex * inv, ey * inv, ez * inv, ew * inv};
    }
}

// ---------------------------------------------------------------- launch

extern "C" void kernel_launch(void* const* d_in, const int* in_sizes, int n_in,
                              void* d_out, int out_size, void* d_ws, size_t ws_size,
                              hipStream_t stream) {
    const float* enc = (const float*)d_in[0];
    const float* tra1 = (const float*)d_in[1];
    const float* tra2 = (const float*)d_in[2];
    const float* tra3 = (const float*)d_in[3];
    const float* z = (const float*)d_in[4];
    const int* erow = (const int*)d_in[5];
    const int* ecol = (const int*)d_in[6];
    const float* evals = (const float*)d_in[7];
    const float* W1 = (const float*)d_in[8];
    const float* W2 = (const float*)d_in[9];
    const float* W3 = (const float*)d_in[10];
    const float* W4 = (const float*)d_in[11];
    const float* W5 = (const float*)d_in[12];
    const float* cluster = (const float*)d_in[13];
    float* out = (float*)d_out;

    char* ws = (char*)d_ws;
    size_t off = 0;
    auto take = [&](size_t bytes) -> void* {
        void* p = ws + off;
        off = (off + bytes + 255) & ~(size_t)255;
        return p;
    };
    int* counts = (int*)take((size_t)NN * 4);
    int* cursor = (int*)take((size_t)NN * 4);
    int* offs = (int*)take((size_t)(NN + 1) * 4);
    int* bsum = (int*)take(4096);
    int2* edges = (int2*)take((size_t)NE * 8);
    _Float16* Xa = (_Float16*)take((size_t)MPAD * DD * 2);
    _Float16* Xb = (_Float16*)take((size_t)MPAD * DD * 2);
    _Float16* Wt = (_Float16*)take((size_t)4 * DD * DD * 2);
    float* Y5 = (float*)take((size_t)NN * KC * 4);

    hipMemsetAsync(counts, 0, (size_t)NN * 4, stream);
    hipMemsetAsync(cursor, 0, (size_t)NN * 4, stream);

    k_hist<<<(NE + 255) / 256, 256, 0, stream>>>(erow, counts);
    const int nsb = (NN + 1023) / 1024;  // 98
    k_scan1<<<nsb, 256, 0, stream>>>(counts, offs, bsum);
    k_scan2<<<1, 64, 0, stream>>>(bsum, nsb);
    k_scan3<<<(NN + 256) / 256, 256, 0, stream>>>(offs, bsum);
    k_fill<<<(NE + 255) / 256, 256, 0, stream>>>(erow, ecol, evals, offs, cursor, edges);

    k_cvtX<<<(NN * DD / 8 + 255) / 256, 256, 0, stream>>>(enc, Xa);
    k_cvtW<<<dim3(8, 8, 4), 256, 0, stream>>>(W1, W2, W3, W4, Wt);

    const int gb = MPAD / 128;  // 782
    const int rb = NN / 4;      // 25000

    k_gemm_h<<<gb, 512, 0, stream>>>(Xa, Wt + 0 * DD * DD, Xb);
    k_spmm_h<<<rb, 256, 0, stream>>>(offs, edges, Xb, tra1, Xa);

    k_gemm_h<<<gb, 512, 0, stream>>>(Xa, Wt + 1 * DD * DD, Xb);
    k_spmm_h<<<rb, 256, 0, stream>>>(offs, edges, Xb, tra2, Xa);

    k_gemm_h<<<gb, 512, 0, stream>>>(Xa, Wt + 2 * DD * DD, Xb);
    k_spmm_h<<<rb, 256, 0, stream>>>(offs, edges, Xb, tra3, Xa);

    k_gemm_h<<<gb, 512, 0, stream>>>(Xa, Wt + 3 * DD * DD, Xb);
    k_spmm_last<<<rb, 256, 0, stream>>>(offs, edges, Xb, z, W5, cluster, Y5, out);

    k_sm5<<<rb, 256, 0, stream>>>(offs, edges, Y5, out);
}